// Round 1
// baseline (5500.253 us; speedup 1.0000x reference)
//
#include <hip/hip_runtime.h>
#include <math.h>

// CRsAE1D: 30 FISTA iterations of convolutional sparse coding.
// y [32,1,8192] f32, H [64,1,31] f32 (pre-normalized by setup).
// out = concat(y_hat [32,1,8192], x [32,64,8162]) f32.
//
// Strategy: one fused kernel per FISTA iteration (kernel boundary = global
// barrier). Each block owns (batch b, 256-wide m-tile), computes the
// soft-threshold update from the staged residual, then scatter-accumulates
// this tile's contribution to Hop(x_tmp_{t+1}) into a rotating residual
// buffer with global atomics. x_old lives in d_out's x-region so the final
// x lands in place.

#define BB   32
#define CCH  64
#define KF   31
#define NN   8192
#define MM   8162
#define TT   30
#define TILE 256

#define BCM ((size_t)BB * CCH * MM)   // 16,715,776
#define BN  ((size_t)BB * NN)         // 262,144

// LDS index swizzle: +1 slot every 32 to break stride-8 bank conflicts
__device__ __forceinline__ int F(int i) { return i + (i >> 5); }

__global__ __launch_bounds__(256) void step_kernel(
    const float* __restrict__ y, const float* __restrict__ Hg,
    float* __restrict__ xtmp, float* __restrict__ xold,
    const float* __restrict__ rcur, float* __restrict__ rnext,
    float* __restrict__ rzero, float coef)
{
    __shared__ float Hs[CCH * 32];   // H padded to 32 taps (tap 31 = 0)
    __shared__ float resv[296];      // res window, swizzled, logical 288
    __shared__ float racc[288];      // Hop(x_tmp_next) partial for this tile

    const int tid  = threadIdx.x;
    const int tile = blockIdx.x;
    const int b    = blockIdx.y;
    const int m0   = tile * TILE;
    const size_t ybase = (size_t)b * NN;

    // ---- phase 0: staging ----
    for (int s = tid; s < CCH * 32; s += 256) {
        int c = s >> 5, k = s & 31;
        Hs[s] = (k < KF) ? Hg[c * KF + k] : 0.f;
    }
    for (int i = tid; i < 288; i += 256) {
        int n = m0 + i;
        float v = 0.f;
        if (n < NN) v = y[ybase + n] - rcur[ybase + n];   // res = y - Hop(x_tmp)
        resv[F(i)] = v;
        racc[i] = 0.f;
    }
    // zero the buffer that iteration t+2 will accumulate into
    rzero[ybase + m0 + tid] = 0.f;
    __syncthreads();

    // ---- phase 1: x update (31-tap correlation via circular reg window) ----
    const int lanem = tid & 31;      // 32 m-groups of 8
    const int lb    = lanem * 8;
    const int cb    = tid >> 5;      // 8 channels per pass
    const int mb    = m0 + lb;

    #pragma unroll 1
    for (int p = 0; p < 8; ++p) {
        int c = p * 8 + cb;
        float w[8], acc[8];
        #pragma unroll
        for (int j = 0; j < 8; ++j) { w[j] = resv[F(lb + j)]; acc[j] = 0.f; }
        #pragma unroll
        for (int k = 0; k < 32; ++k) {
            float h = Hs[c * 32 + k];
            #pragma unroll
            for (int j = 0; j < 8; ++j) acc[j] = fmaf(w[(k + j) & 7], h, acc[j]);
            w[k & 7] = resv[F(lb + k + 8)];   // max idx 287, sized
        }
        size_t gbase = ((size_t)(b * CCH + c)) * MM + mb;
        if (mb + 7 < MM) {
            float xtv[8], xov[8], xnw[8];
            #pragma unroll
            for (int j = 0; j < 8; j += 2) {
                float2 a = *(const float2*)(xtmp + gbase + j);
                float2 o = *(const float2*)(xold + gbase + j);
                xtv[j] = a.x; xtv[j + 1] = a.y;
                xov[j] = o.x; xov[j + 1] = o.y;
            }
            #pragma unroll
            for (int j = 0; j < 8; ++j) {
                float xn = fmaf(acc[j], 0.2f, xtv[j]) - 0.02f;   // + HT/L - lam/L
                xn = fmaxf(xn, 0.f);
                xnw[j] = fmaf(coef, xn - xov[j], xn);            // momentum
                xov[j] = xn;                                     // new x_old
            }
            #pragma unroll
            for (int j = 0; j < 8; j += 2) {
                *(float2*)(xold + gbase + j) = make_float2(xov[j], xov[j + 1]);
                *(float2*)(xtmp + gbase + j) = make_float2(xnw[j], xnw[j + 1]);
            }
        } else {
            #pragma unroll
            for (int j = 0; j < 8; ++j) {
                int m = mb + j;
                if (m < MM) {
                    float a = xtmp[gbase + j], o = xold[gbase + j];
                    float xn = fmaxf(fmaf(acc[j], 0.2f, a) - 0.02f, 0.f);
                    xold[gbase + j] = xn;
                    xtmp[gbase + j] = fmaf(coef, xn - o, xn);
                }
            }
        }
    }
    __syncthreads();   // make this block's xtmp writes visible (same CU L1)

    // ---- phase 2: gather Hop(x_tmp_next) over own tile, accumulate ----
    const int vlim = (MM - m0 < TILE) ? (MM - m0) : TILE;
    #pragma unroll 1
    for (int tau = tid; tau < 288; tau += 256) {
        int ng = tau % 72, cg = tau / 72;
        int ib = ng * 4;
        float r4[4] = {0.f, 0.f, 0.f, 0.f};
        #pragma unroll 1
        for (int cc2 = 0; cc2 < 16; ++cc2) {
            int c = cg * 16 + cc2;
            const float* xr = xtmp + ((size_t)(b * CCH + c)) * MM + m0;
            float w4[4];
            #pragma unroll
            for (int j = 0; j < 4; ++j) {
                int ix = ib + j;
                w4[j] = (ix < vlim) ? xr[ix] : 0.f;
            }
            #pragma unroll
            for (int k = 0; k < KF; ++k) {
                float h = Hs[c * 32 + k];
                #pragma unroll
                for (int j = 0; j < 4; ++j)
                    r4[j] = fmaf(w4[(j - k) & 3], h, r4[j]);
                int ix = ib - k - 1;
                w4[(3 - k) & 3] = ((unsigned)ix < (unsigned)vlim) ? xr[ix] : 0.f;
            }
        }
        #pragma unroll
        for (int j = 0; j < 4; ++j) {
            int i = ib + j;
            if (i < 286) atomicAdd(&racc[i], r4[j]);
        }
    }
    __syncthreads();
    for (int i = tid; i < 286; i += 256) {
        int n = m0 + i;
        if (n < NN) atomicAdd(&rnext[ybase + n], racc[i]);
    }
}

// y_hat = Hop(x_final); x_final read from d_out's x-region.
__global__ __launch_bounds__(256) void final_kernel(
    const float* __restrict__ xf, const float* __restrict__ Hg,
    float* __restrict__ yhat)
{
    __shared__ float Hf[CCH * 32];   // flipped taps: Hf[c][kk] = H[c][30-kk]
    __shared__ float racc[256];

    const int tid = threadIdx.x;
    const int n0  = blockIdx.x * 256;
    const int b   = blockIdx.y;

    for (int s = tid; s < CCH * 32; s += 256) {
        int c = s >> 5, kk = s & 31;
        Hf[s] = (kk < KF) ? Hg[c * KF + (KF - 1 - kk)] : 0.f;
    }
    racc[tid] = 0.f;
    __syncthreads();

    const int ng = tid & 63, cg = tid >> 6;
    const int ib = ng * 4;
    float r4[4] = {0.f, 0.f, 0.f, 0.f};
    #pragma unroll 1
    for (int cc2 = 0; cc2 < 16; ++cc2) {
        int c = cg * 16 + cc2;
        const float* xr = xf + ((size_t)(b * CCH + c)) * MM + (n0 - 30);
        float w4[4];
        #pragma unroll
        for (int j = 0; j < 4; ++j) {
            int jj = ib + j, m = n0 - 30 + jj;
            w4[j] = ((unsigned)m < MM) ? xr[jj] : 0.f;
        }
        #pragma unroll
        for (int kk = 0; kk < 32; ++kk) {
            float h = Hf[c * 32 + kk];
            #pragma unroll
            for (int j = 0; j < 4; ++j)
                r4[j] = fmaf(w4[(kk + j) & 3], h, r4[j]);
            int jj = ib + kk + 4, m = n0 - 30 + jj;
            w4[kk & 3] = ((unsigned)m < MM) ? xr[jj] : 0.f;
        }
    }
    #pragma unroll
    for (int j = 0; j < 4; ++j) atomicAdd(&racc[ib + j], r4[j]);
    __syncthreads();
    yhat[(size_t)b * NN + n0 + tid] = racc[tid];
}

extern "C" void kernel_launch(void* const* d_in, const int* in_sizes, int n_in,
                              void* d_out, int out_size, void* d_ws, size_t ws_size,
                              hipStream_t stream) {
    const float* y  = (const float*)d_in[0];
    const float* Hg = (const float*)d_in[1];

    float* out  = (float*)d_out;
    float* yhat = out;                       // B*N
    float* xout = out + BN;                  // B*C*M, doubles as x_old buffer

    float* xtmp = (float*)d_ws;              // B*C*M
    float* r0   = xtmp + BCM;                // 3 rotating Hop-accumulators, B*N each
    float* r1   = r0 + BN;
    float* r2   = r1 + BN;
    float* rb[3] = {r0, r1, r2};

    // init: x_tmp = 0, x_old = 0, residual accumulators = 0
    hipMemsetAsync(xtmp, 0, (BCM + 3 * BN) * sizeof(float), stream);
    hipMemsetAsync(xout, 0, BCM * sizeof(float), stream);

    dim3 grid(NN / TILE, BB);   // 32 tiles x 32 batch
    float s = 1.f;
    for (int t = 0; t < TT; ++t) {
        float snew = (1.f + sqrtf(1.f + 4.f * s * s)) * 0.5f;
        float coef = (s - 1.f) / snew;
        step_kernel<<<grid, 256, 0, stream>>>(
            y, Hg, xtmp, xout,
            rb[t % 3], rb[(t + 1) % 3], rb[(t + 2) % 3], coef);
        s = snew;
    }
    final_kernel<<<grid, 256, 0, stream>>>(xout, Hg, yhat);
}

// Round 2
// 3922.093 us; speedup vs baseline: 1.4024x; 1.4024x over previous
//
#include <hip/hip_runtime.h>
#include <math.h>

// CRsAE1D: 30 FISTA iterations. y [32,1,8192] f32, H [64,1,31] f32.
// out = concat(y_hat [32,8192], x [32,64,8162]) f32.
//
// Per-iteration fused kernel. State = x_new only (ping-pong between ws and
// d_out's x-region); x_tmp is recomputed from (x_new_{t-1}, x_new_{t-2}) so
// global traffic is 2 reads + 1 write of 67MB. Phase 2 (Hop scatter) gathers
// from an LDS-staged x_tmp_{t+1} tile (zero-padded halo -> no predication,
// no serial global-load chains). t=29 uses beta=0 and rnext=yhat so the
// final Hop(x_final) lands directly in y_hat (no extra kernel).

#define BB   32
#define CCH  64
#define KF   31
#define NN   8192
#define MM   8162
#define TT   30
#define TILE 256
#define NT   32          // NN/TILE
#define RC   16          // channels per round
#define NR   4           // rounds

#define XS_COLS 336      // covers F(319)=328
#define HS_P    33       // Hs pitch: (33c+k)%32=(c+k)%32 -> bank spread

#define BCM ((size_t)BB * CCH * MM)
#define BN  ((size_t)BB * NN)

// LDS swizzle: +1 slot every 32 breaks power-of-2 stride conflicts
__device__ __forceinline__ int F(int i) { return i + (i >> 5); }

__global__ __launch_bounds__(256) void step_kernel(
    const float* __restrict__ y, const float* __restrict__ Hg,
    const float* __restrict__ xA,  // x_new_{t-1}
    float* __restrict__ xW,        // read: x_new_{t-2}; write: x_new_t
    const float* __restrict__ rcur, float* __restrict__ rnext,
    float* __restrict__ rzero, float c0, float c1)
{
    __shared__ float Hs[CCH * HS_P];     // 8448 B
    __shared__ float resv[296];          // res window, swizzled
    __shared__ float xs[RC * XS_COLS];   // x_tmp_{t+1} tile (16 ch/round), 21504 B
    __shared__ float racc[288];          // Hop partial for this tile

    const int tid = threadIdx.x;
    const int m0  = blockIdx.x * TILE;
    const int b   = blockIdx.y;
    const size_t yb = (size_t)b * NN;

    // ---- phase 0: staging ----
    for (int s = tid; s < CCH * HS_P; s += 256) {
        int c = s / HS_P, k = s - c * HS_P;
        Hs[s] = (k < KF) ? Hg[c * KF + k] : 0.f;
    }
    for (int i = tid; i < 288; i += 256) {
        int n = m0 + i; float v = 0.f;
        if (i < 286 && n < NN) v = y[yb + n] - rcur[yb + n];
        resv[F(i)] = v;
        racc[i] = 0.f;
    }
    // zero xs halo pads: raw [0,32) and [288,320) per row (persist all rounds)
    for (int s = tid; s < RC * 64; s += 256) {
        int row = s >> 6, q = s & 63;
        int raw = (q < 32) ? q : (q + 256);
        xs[row * XS_COLS + F(raw)] = 0.f;
    }
    rzero[yb + m0 + tid] = 0.f;   // pre-zero the t+2 accumulator
    __syncthreads();

    const int cb    = tid >> 4;   // phase 1: channel slot 0..15
    const int lanem = tid & 15;   // phase 1: m-group
    const int ogi   = tid & 31;   // phase 2: output group (9 outputs)
    const int csi   = tid >> 5;   // phase 2: channel-pair group

    for (int r = 0; r < NR; ++r) {
        // ---- phase 1: x update for channels [r*16, r*16+16) ----
        const int c = r * RC + cb;
        const size_t xrow = ((size_t)(b * CCH + c)) * MM;
        #pragma unroll
        for (int p = 0; p < 2; ++p) {
            const int lb = p * 128 + lanem * 8;
            const int mb = m0 + lb;
            const size_t g = xrow + mb;
            const bool fast = (mb + 7 < MM);
            float av[8], bv[8];
            if (fast) {   // issue global loads early; hide under ring compute
                #pragma unroll
                for (int j = 0; j < 8; j += 2) {
                    float2 t2 = *(const float2*)(xA + g + j);
                    av[j] = t2.x; av[j + 1] = t2.y;
                }
                #pragma unroll
                for (int j = 0; j < 8; j += 2) {
                    float2 t2 = *(const float2*)(xW + g + j);
                    bv[j] = t2.x; bv[j + 1] = t2.y;
                }
            }
            float w[8], acc[8];
            #pragma unroll
            for (int j = 0; j < 8; ++j) { w[j] = resv[F(lb + j)]; acc[j] = 0.f; }
            #pragma unroll
            for (int k = 0; k < KF; ++k) {
                float h = Hs[c * HS_P + k];
                #pragma unroll
                for (int j = 0; j < 8; ++j) acc[j] = fmaf(w[(k + j) & 7], h, acc[j]);
                w[k & 7] = resv[F(lb + k + 8)];
            }
            if (fast) {
                float xn[8], xt1[8];
                #pragma unroll
                for (int j = 0; j < 8; ++j) {
                    float xt = fmaf(c0, av[j] - bv[j], av[j]);     // x_tmp_t
                    float v  = fmaf(acc[j], 0.2f, xt) - 0.02f;     // +HT/L - lam/L
                    xn[j]  = fmaxf(v, 0.f);
                    xt1[j] = fmaf(c1, xn[j] - av[j], xn[j]);       // x_tmp_{t+1}
                }
                #pragma unroll
                for (int j = 0; j < 8; j += 2)
                    *(float2*)(xW + g + j) = make_float2(xn[j], xn[j + 1]);
                #pragma unroll
                for (int j = 0; j < 8; ++j)
                    xs[cb * XS_COLS + F(32 + lb + j)] = xt1[j];
            } else {
                #pragma unroll
                for (int j = 0; j < 8; ++j) {
                    float xt1j = 0.f;
                    if (mb + j < MM) {
                        float a = xA[g + j], b2 = xW[g + j];
                        float xt = fmaf(c0, a - b2, a);
                        float xn = fmaxf(fmaf(acc[j], 0.2f, xt) - 0.02f, 0.f);
                        xW[g + j] = xn;
                        xt1j = fmaf(c1, xn - a, xn);
                    }
                    xs[cb * XS_COLS + F(32 + lb + j)] = xt1j;
                }
            }
        }
        __syncthreads();

        // ---- phase 2: Hop gather from LDS, 1 item/thread (9 out x 2 ch) ----
        {
            const int ib   = ogi * 9;
            const int crow = csi * 2;
            const int cg   = r * RC + crow;
            float r9[9];
            #pragma unroll
            for (int j = 0; j < 9; ++j) r9[j] = 0.f;
            #pragma unroll
            for (int cc = 0; cc < 2; ++cc) {
                const float* xr = xs + (crow + cc) * XS_COLS;
                const float* hr = Hs + (cg + cc) * HS_P;
                float w[16];
                #pragma unroll
                for (int j = 0; j < 9; ++j) w[j] = xr[F(32 + ib + j)];
                #pragma unroll
                for (int k = 0; k < KF; ++k) {
                    float h = hr[k];
                    #pragma unroll
                    for (int j = 0; j < 9; ++j)
                        r9[j] = fmaf(w[(j - k) & 15], h, r9[j]);
                    w[(15 - k) & 15] = xr[F(31 + ib - k)];   // x[ib-k-1], in-bounds
                }
            }
            #pragma unroll
            for (int j = 0; j < 9; ++j) {
                int i = ib + j;
                if (i < 286) atomicAdd(&racc[i], r9[j]);
            }
        }
        __syncthreads();
    }

    // ---- flush: tile's Hop contribution -> global accumulator ----
    for (int i = tid; i < 286; i += 256) {
        int n = m0 + i;
        if (n < NN) atomicAdd(&rnext[yb + n], racc[i]);
    }
}

extern "C" void kernel_launch(void* const* d_in, const int* in_sizes, int n_in,
                              void* d_out, int out_size, void* d_ws, size_t ws_size,
                              hipStream_t stream) {
    const float* y  = (const float*)d_in[0];
    const float* Hg = (const float*)d_in[1];

    float* out  = (float*)d_out;
    float* yhat = out;               // B*N
    float* xout = out + BN;          // B*C*M : ping-pong buffer X1 (odd t)
    float* x0w  = (float*)d_ws;      // B*C*M : ping-pong buffer X0 (even t)
    float* r0   = x0w + BCM;         // 3 rotating Hop accumulators, B*N each
    float* r1   = r0 + BN;
    float* r2   = r1 + BN;
    float* rb[3] = {r0, r1, r2};

    hipMemsetAsync(x0w, 0, (BCM + 3 * BN) * sizeof(float), stream);
    hipMemsetAsync(out, 0, (BN + BCM) * sizeof(float), stream);

    dim3 grid(NT, BB);   // 32 tiles x 32 batch = 1024 blocks (4/CU exact)
    float s = 1.f, beta_prev = 0.f;
    for (int t = 0; t < TT; ++t) {
        float snew = (1.f + sqrtf(1.f + 4.f * s * s)) * 0.5f;
        float beta = (s - 1.f) / snew;
        float c1 = (t == TT - 1) ? 0.f : beta;           // t=29: Hop(x_new)=y_hat
        float* xWt       = (t & 1) ? xout : x0w;
        const float* xAt = (t & 1) ? x0w  : xout;
        float* rnext = (t == TT - 1) ? yhat : rb[(t + 1) % 3];
        step_kernel<<<grid, 256, 0, stream>>>(y, Hg, xAt, xWt,
            rb[t % 3], rnext, rb[(t + 2) % 3], beta_prev, c1);
        beta_prev = beta;
        s = snew;
    }
}